// Round 5
// baseline (1457.221 us; speedup 1.0000x reference)
//
#include <hip/hip_runtime.h>
#include <hip/hip_bf16.h>
#include <cstdint>
#include <cstddef>

#define HIST    256
#define DMODEL  512
#define DINNER  1024
#define DSTATE  16
#define DTRANK  32
#define OBSDIM  4096
#define OBSOUT  448
#define ADIM    64
#define NLAYERS 4
#define MROWS   8192   // BATCH*HIST

typedef __bf16  bf16x8 __attribute__((ext_vector_type(8)));
typedef float   f32x4  __attribute__((ext_vector_type(4)));

enum { MEPI_TOK = 0, MEPI_BF16 = 1, MEPI_SPLIT = 2, MEPI_RELUF = 3 };

__device__ __forceinline__ float siluf(float x) { return x / (1.f + __expf(-x)); }
__device__ __forceinline__ float softplusf(float x) {
    return fmaxf(x, 0.f) + log1pf(__expf(-fabsf(x)));
}

// ---------------------------------------------------------------------------
// bf16 MFMA GEMM, 128x128 tile, BK=32 (m97-style global_load_lds staging).
template<int EPI>
__global__ __launch_bounds__(256)
void gemm_mfma(const __hip_bfloat16* __restrict__ A, int lda,
               const __hip_bfloat16* __restrict__ W,
               float* __restrict__ Cf, int ldc,
               __hip_bfloat16* __restrict__ Cb, int ldcb,
               float* __restrict__ C2,
               int coff, int N, int K,
               const float* __restrict__ bias, const float* __restrict__ pos)
{
    __shared__ __hip_bfloat16 Asm[128 * 32];
    __shared__ __hip_bfloat16 Bsm[128 * 32];
    const int tid  = threadIdx.x;
    const int lane = tid & 63;
    const int wv   = tid >> 6;
    const int m0   = blockIdx.y * 128;
    const int n0   = blockIdx.x * 128;
    const int wm   = (wv >> 1) << 6;
    const int wn   = (wv & 1) << 6;
    const int sr   = lane >> 2;
    const int sc   = (lane & 3) << 3;
    const int quad = lane >> 4;
    const int c16  = lane & 15;

    f32x4 acc[4][4] = {};
    const __hip_bfloat16* aptr = A + (size_t)(m0 + wv * 16 + sr) * lda + sc;
    const __hip_bfloat16* bptr = W + (size_t)(n0 + wv * 16 + sr) * K + sc;
    __hip_bfloat16* asml = Asm + wv * 16 * 32;
    __hip_bfloat16* bsml = Bsm + wv * 16 * 32;

    for (int k0 = 0; k0 < K; k0 += 32) {
        __syncthreads();
        __builtin_amdgcn_global_load_lds(
            (const __attribute__((address_space(1))) void*)(aptr + k0),
            (__attribute__((address_space(3))) void*)(asml), 16, 0, 0);
        __builtin_amdgcn_global_load_lds(
            (const __attribute__((address_space(1))) void*)(aptr + (size_t)64 * lda + k0),
            (__attribute__((address_space(3))) void*)(asml + 64 * 32), 16, 0, 0);
        __builtin_amdgcn_global_load_lds(
            (const __attribute__((address_space(1))) void*)(bptr + k0),
            (__attribute__((address_space(3))) void*)(bsml), 16, 0, 0);
        __builtin_amdgcn_global_load_lds(
            (const __attribute__((address_space(1))) void*)(bptr + (size_t)64 * K + k0),
            (__attribute__((address_space(3))) void*)(bsml + 64 * 32), 16, 0, 0);
        __syncthreads();

        bf16x8 af[4], bfr[4];
        #pragma unroll
        for (int i = 0; i < 4; ++i) {
            af[i]  = *(const bf16x8*)(Asm + (wm + i * 16 + c16) * 32 + quad * 8);
            bfr[i] = *(const bf16x8*)(Bsm + (wn + i * 16 + c16) * 32 + quad * 8);
        }
        #pragma unroll
        for (int i = 0; i < 4; ++i)
            #pragma unroll
            for (int j = 0; j < 4; ++j)
                acc[i][j] = __builtin_amdgcn_mfma_f32_16x16x32_bf16(af[i], bfr[j], acc[i][j], 0, 0, 0);
    }

    #pragma unroll
    for (int i = 0; i < 4; ++i) {
        const int mbase = m0 + wm + i * 16 + quad * 4;
        #pragma unroll
        for (int j = 0; j < 4; ++j) {
            const int n = n0 + wn + j * 16 + c16;
            if (n < N) {
                #pragma unroll
                for (int r = 0; r < 4; ++r) {
                    const size_t m = mbase + r;
                    float v = acc[i][j][r];
                    if (EPI == MEPI_TOK) {
                        v += bias[n] + pos[(m & (HIST - 1)) * DMODEL + coff + n];
                        Cb[m * ldcb + coff + n] = __float2bfloat16(v);
                    } else if (EPI == MEPI_BF16) {
                        Cb[m * ldcb + n] = __float2bfloat16(v);
                    } else if (EPI == MEPI_SPLIT) {
                        if (n < DTRANK) Cf[m * 32 + n] = v;
                        else C2[m * 32 + ((n & 15) << 1) + ((n >> 4) & 1)] = v;
                    } else { // MEPI_RELUF
                        Cf[m * ldc + n] = fmaxf(v + bias[n], 0.f);
                    }
                }
            }
        }
    }
}

// ---------------------------------------------------------------------------
// f32 GEMM for W_dt (K=32): dtb = bf16(softplus(xdt @ W_dt^T + b_dt))
__global__ __launch_bounds__(256)
void gemm_f32_sp(const float* __restrict__ A, int lda,
                 const float* __restrict__ W,
                 __hip_bfloat16* __restrict__ C, int ldc,
                 int N, int K, const float* __restrict__ bias)
{
    __shared__ float As[32][68];
    __shared__ float Ws[32][68];
    const int tid = threadIdx.x;
    const int tx = tid & 15, ty = tid >> 4;
    const int m0 = blockIdx.y * 64;
    const int n0 = blockIdx.x * 64;
    const int lr = tid >> 3;
    const int lc = (tid & 7) << 2;
    float acc[4][4] = {};
    for (int k0 = 0; k0 < K; k0 += 32) {
        const float4 a0 = *(const float4*)(A + (size_t)(m0 + lr) * lda + k0 + lc);
        const float4 a1 = *(const float4*)(A + (size_t)(m0 + lr + 32) * lda + k0 + lc);
        const float4 b0 = *(const float4*)(W + (size_t)(n0 + lr) * K + k0 + lc);
        const float4 b1 = *(const float4*)(W + (size_t)(n0 + lr + 32) * K + k0 + lc);
        __syncthreads();
        As[lc+0][lr] = a0.x; As[lc+1][lr] = a0.y; As[lc+2][lr] = a0.z; As[lc+3][lr] = a0.w;
        As[lc+0][lr+32] = a1.x; As[lc+1][lr+32] = a1.y; As[lc+2][lr+32] = a1.z; As[lc+3][lr+32] = a1.w;
        Ws[lc+0][lr] = b0.x; Ws[lc+1][lr] = b0.y; Ws[lc+2][lr] = b0.z; Ws[lc+3][lr] = b0.w;
        Ws[lc+0][lr+32] = b1.x; Ws[lc+1][lr+32] = b1.y; Ws[lc+2][lr+32] = b1.z; Ws[lc+3][lr+32] = b1.w;
        __syncthreads();
        #pragma unroll
        for (int k = 0; k < 32; ++k) {
            const float4 a4 = *(const float4*)&As[k][ty << 2];
            const float4 b4 = *(const float4*)&Ws[k][tx << 2];
            const float a[4] = {a4.x, a4.y, a4.z, a4.w};
            const float b[4] = {b4.x, b4.y, b4.z, b4.w};
            #pragma unroll
            for (int i = 0; i < 4; ++i)
                #pragma unroll
                for (int j = 0; j < 4; ++j)
                    acc[i][j] = fmaf(a[i], b[j], acc[i][j]);
        }
    }
    const int mb = m0 + (ty << 2);
    const int nb = n0 + (tx << 2);
    #pragma unroll
    for (int i = 0; i < 4; ++i) {
        const size_t m = mb + i;
        #pragma unroll
        for (int j = 0; j < 4; ++j) {
            const int n = nb + j;
            C[m * ldc + n] = __float2bfloat16(softplusf(acc[i][j] + bias[n]));
        }
    }
}

// ---------------------------------------------------------------------------
__global__ __launch_bounds__(256)
void cast_bf16_kernel(const float* __restrict__ src, __hip_bfloat16* __restrict__ dst, int n4)
{
    const int i = blockIdx.x * 256 + threadIdx.x;
    if (i >= n4) return;
    const float4 v = ((const float4*)src)[i];
    union { __hip_bfloat16 h[4]; short4 s; } o;
    o.h[0] = __float2bfloat16(v.x); o.h[1] = __float2bfloat16(v.y);
    o.h[2] = __float2bfloat16(v.z); o.h[3] = __float2bfloat16(v.w);
    ((short4*)dst)[i] = o.s;
}

__global__ __launch_bounds__(256)
void cast_pad_kernel(const float* __restrict__ src, __hip_bfloat16* __restrict__ dst,
                     int nrows, int K4, int total4)
{
    const int i = blockIdx.x * 256 + threadIdx.x;
    if (i >= total4) return;
    const int row = i / K4;
    float4 v = make_float4(0.f, 0.f, 0.f, 0.f);
    if (row < nrows) v = ((const float4*)src)[i];
    union { __hip_bfloat16 h[4]; short4 s; } o;
    o.h[0] = __float2bfloat16(v.x); o.h[1] = __float2bfloat16(v.y);
    o.h[2] = __float2bfloat16(v.z); o.h[3] = __float2bfloat16(v.w);
    ((short4*)dst)[i] = o.s;
}

__global__ __launch_bounds__(256)
void embed_kernel(const int* __restrict__ actions, const float* __restrict__ act_emb,
                  const float* __restrict__ pos_emb, __hip_bfloat16* __restrict__ xb)
{
    const int idx = blockIdx.x * 256 + threadIdx.x;   // MROWS*64
    const int e = idx & 63;
    const int m = idx >> 6;
    const int l = m & (HIST - 1);
    const int b = m >> 8;
    float v = pos_emb[l * DMODEL + e];
    if (l > 0) {
        const int a = actions[b * HIST + l - 1];
        v += act_emb[a * ADIM + e];
    }
    xb[(size_t)m * DMODEL + e] = __float2bfloat16(v);
}

// xcb[m,d] = bf16(silu(conv_b[d] + sum_k conv_w[d,k]*xi[l-3+k, d]))
__global__ __launch_bounds__(256)
void conv_silu_kernel(const __hip_bfloat16* __restrict__ xzb, const float* __restrict__ cw,
                      const float* __restrict__ cb, __hip_bfloat16* __restrict__ xcb)
{
    const int idx = blockIdx.x * 256 + threadIdx.x;   // MROWS*DINNER
    const int d = idx & (DINNER - 1);
    const int m = idx >> 10;
    const int l = m & (HIST - 1);
    const float4 w = ((const float4*)cw)[d];
    const __hip_bfloat16* basep = xzb + (size_t)m * (2 * DINNER) + d;
    float acc = cb[d] + w.w * __bfloat162float(basep[0]);
    if (l >= 1) acc = fmaf(w.z, __bfloat162float(basep[-2 * DINNER]), acc);
    if (l >= 2) acc = fmaf(w.y, __bfloat162float(basep[-4 * DINNER]), acc);
    if (l >= 3) acc = fmaf(w.x, __bfloat162float(basep[-6 * DINNER]), acc);
    xcb[idx] = __float2bfloat16(siluf(acc));
}

// ---------------------------------------------------------------------------
// Selective scan, software-pipelined. Wave = 4 channel-groups x 16 state-lanes.
// Each 16-step block's operands (16x float2 (B,C) + dt/xc/z) are preloaded
// into REGISTERS; the next block's loads are issued before the current block's
// compute (2-deep ping-pong, unrolled x2). LDS only broadcasts (dt, dt*xc)
// within each 16-lane group (double-buffered slot); reduction via DPP.
__device__ __forceinline__ float dpp_add(float x, const int ctrl) {
    switch (ctrl) {
    case 0xB1:  return x + __int_as_float(__builtin_amdgcn_update_dpp(0, __float_as_int(x), 0xB1, 0xF, 0xF, true));
    case 0x4E:  return x + __int_as_float(__builtin_amdgcn_update_dpp(0, __float_as_int(x), 0x4E, 0xF, 0xF, true));
    case 0x141: return x + __int_as_float(__builtin_amdgcn_update_dpp(0, __float_as_int(x), 0x141, 0xF, 0xF, true));
    default:    return x + __int_as_float(__builtin_amdgcn_update_dpp(0, __float_as_int(x), 0x140, 0xF, 0xF, true));
    }
}

__global__ __launch_bounds__(256, 4)
void scan_kernel(const __hip_bfloat16* __restrict__ dtb, const float* __restrict__ bc,
                 const __hip_bfloat16* __restrict__ xcb, const __hip_bfloat16* __restrict__ zb,
                 const float* __restrict__ A_log, const float* __restrict__ D_p,
                 __hip_bfloat16* __restrict__ yb)
{
    __shared__ float2 bls[2][4][4][17];   // [phase][wave][chan-group][j]
    const int tid = threadIdx.x;
    const int n   = tid & 15;
    const int wv  = tid >> 6;
    const int cg  = (tid >> 4) & 3;
    const int c = blockIdx.x * 16 + (tid >> 4);  // global channel (b,d)
    const int b = c >> 10;
    const int d = c & (DINNER - 1);
    const float A = -__expf(A_log[d * DSTATE + n]);
    const float Dp = D_p[d];
    float h = 0.f;
    const size_t row0 = (size_t)b * HIST;

    float2 bcvA[16], bcvB[16];
    float dtA, xcA, zA, dtB, xcB, zB;

#define LOADBLK(L0, BCV, DT, XC, Z) { \
        const size_t rj_ = row0 + (L0) + n; \
        DT = __bfloat162float(dtb[rj_ * DINNER + d]); \
        XC = __bfloat162float(xcb[rj_ * DINNER + d]); \
        Z  = __bfloat162float(zb [rj_ * 2 * DINNER + d]); \
        const float* p_ = bc + (row0 + (L0)) * 32 + 2 * n; \
        _Pragma("unroll") \
        for (int j_ = 0; j_ < 16; ++j_) BCV[j_] = *(const float2*)(p_ + j_ * 32); \
    }

#define COMPUTEBLK(L0, BCV, DT, XC, Z, PH) { \
        bls[PH][wv][cg][n] = make_float2(DT, DT * XC); \
        float yreg = 0.f; \
        _Pragma("unroll") \
        for (int J = 0; J < 16; ++J) { \
            const float2 bq = bls[PH][wv][cg][J]; \
            const float dA = __expf(bq.x * A); \
            h = fmaf(dA, h, bq.y * BCV[J].x); \
            float ctr = h * BCV[J].y; \
            ctr = dpp_add(ctr, 0xB1); \
            ctr = dpp_add(ctr, 0x4E); \
            ctr = dpp_add(ctr, 0x141); \
            ctr = dpp_add(ctr, 0x140); \
            if (n == J) yreg = ctr; \
        } \
        yb[(row0 + (L0) + n) * DINNER + d] = \
            __float2bfloat16((yreg + (XC) * Dp) * siluf(Z)); \
    }

    LOADBLK(0, bcvA, dtA, xcA, zA)
    #pragma unroll 1
    for (int l0 = 0; l0 < HIST; l0 += 32) {
        LOADBLK(l0 + 16, bcvB, dtB, xcB, zB)
        COMPUTEBLK(l0, bcvA, dtA, xcA, zA, 0)
        if (l0 + 32 < HIST) LOADBLK(l0 + 32, bcvA, dtA, xcA, zA)
        COMPUTEBLK(l0 + 16, bcvB, dtB, xcB, zB, 1)
    }
#undef LOADBLK
#undef COMPUTEBLK
}

// out[m,n] = b2[n] + sum_k h[m,k]*W2[n,k]
__global__ __launch_bounds__(256)
void ffn2_kernel(const float* __restrict__ h, const float* __restrict__ W2,
                 const float* __restrict__ b2, float* __restrict__ out)
{
    const int idx = blockIdx.x * 256 + threadIdx.x;   // MROWS*32
    const int n = idx & 31;
    const int m = idx >> 5;
    if (n >= 18) return;
    const float* hr = h + (size_t)m * DMODEL;
    const float* wr = W2 + (size_t)n * DMODEL;
    float acc = b2[n];
    for (int k = 0; k < DMODEL; k += 4) {
        const float4 hv = *(const float4*)(hr + k);
        const float4 wv = *(const float4*)(wr + k);
        acc = fmaf(hv.x, wv.x, acc);
        acc = fmaf(hv.y, wv.y, acc);
        acc = fmaf(hv.z, wv.z, acc);
        acc = fmaf(hv.w, wv.w, acc);
    }
    out[(size_t)m * 18 + n] = acc;
}

extern "C" void kernel_launch(void* const* d_in, const int* in_sizes, int n_in,
                              void* d_out, int out_size, void* d_ws, size_t ws_size,
                              hipStream_t stream)
{
    const float* obss    = (const float*)d_in[0];
    const int*   actions = (const int*)  d_in[1];
    const float* obs_W   = (const float*)d_in[2];
    const float* obs_b   = (const float*)d_in[3];
    const float* act_emb = (const float*)d_in[4];
    const float* pos_emb = (const float*)d_in[5];
    const float* W_in    = (const float*)d_in[6];
    const float* conv_w  = (const float*)d_in[7];
    const float* conv_b  = (const float*)d_in[8];
    const float* W_x     = (const float*)d_in[9];
    const float* W_dt    = (const float*)d_in[10];
    const float* b_dt    = (const float*)d_in[11];
    const float* A_log   = (const float*)d_in[12];
    const float* D_p     = (const float*)d_in[13];
    const float* W_out   = (const float*)d_in[14];
    const float* ffn_W1  = (const float*)d_in[15];
    const float* ffn_b1  = (const float*)d_in[16];
    const float* ffn_W2  = (const float*)d_in[17];
    const float* ffn_b2  = (const float*)d_in[18];
    float* out = (float*)d_out;

    // Workspace (MiB offsets, lifetime-aliased):
    //  0-8    xb   (bf16 M x 512)        8-40   xzb (bf16 M x 2048: xi|z)
    //  40-56  xcb  (bf16 M x 1024)       56-72  dtb (bf16 M x 1024)
    //  88-104 yb   (bf16 M x 1024)       104-105 xdt (f32 M x 32)
    //  105-106 bcbuf (f32 M x 32)        106-110 wbuf (bf16 weight scratch)
    //  110-110.25 wxb (bf16 128 x 1024)
    //  prologue: obssb @8-72;  epilogue: hbuf @8-24
    const size_t MiB = 1024 * 1024;
    char* base = (char*)d_ws;
    __hip_bfloat16* xb    = (__hip_bfloat16*)(base);
    __hip_bfloat16* xzb   = (__hip_bfloat16*)(base + 8 * MiB);
    __hip_bfloat16* xcb   = (__hip_bfloat16*)(base + 40 * MiB);
    __hip_bfloat16* dtb   = (__hip_bfloat16*)(base + 56 * MiB);
    __hip_bfloat16* yb    = (__hip_bfloat16*)(base + 88 * MiB);
    float*          xdt   = (float*)(base + 104 * MiB);
    float*          bcbuf = (float*)(base + 105 * MiB);
    __hip_bfloat16* wbuf  = (__hip_bfloat16*)(base + 106 * MiB);
    __hip_bfloat16* wxb   = (__hip_bfloat16*)(base + 110 * MiB);
    __hip_bfloat16* obssb = (__hip_bfloat16*)(base + 8 * MiB);
    float*          hbuf  = (float*)(base + 8 * MiB);

    // --- prologue ---
    cast_bf16_kernel<<<(MROWS * OBSDIM / 4) / 256, 256, 0, stream>>>(obss, obssb, MROWS * OBSDIM / 4);
    cast_pad_kernel<<<(512 * OBSDIM / 4) / 256, 256, 0, stream>>>(obs_W, wbuf, OBSOUT, OBSDIM / 4, 512 * OBSDIM / 4);
    embed_kernel<<<MROWS * ADIM / 256, 256, 0, stream>>>(actions, act_emb, pos_emb, xb);
    gemm_mfma<MEPI_TOK><<<dim3(4, MROWS / 128), 256, 0, stream>>>(
        obssb, OBSDIM, wbuf, nullptr, 0, xb, DMODEL, nullptr, ADIM, OBSOUT, OBSDIM, obs_b, pos_emb);

    for (int i = 0; i < NLAYERS; ++i) {
        // W_in: xzb = bf16(xb @ W_in^T), ld 2048 (xi | z)
        cast_bf16_kernel<<<(2 * DINNER * DMODEL / 4) / 256, 256, 0, stream>>>(
            W_in + (size_t)i * 2 * DINNER * DMODEL, wbuf, 2 * DINNER * DMODEL / 4);
        gemm_mfma<MEPI_BF16><<<dim3(2 * DINNER / 128, MROWS / 128), 256, 0, stream>>>(
            xb, DMODEL, wbuf, nullptr, 0, xzb, 2 * DINNER, nullptr, 0, 2 * DINNER, DMODEL,
            nullptr, nullptr);
        conv_silu_kernel<<<MROWS * DINNER / 256, 256, 0, stream>>>(
            xzb, conv_w + (size_t)i * DINNER * 4, conv_b + (size_t)i * DINNER, xcb);
        // W_x (mfma, split): xdt = xcb @ W_x^T[:32], bcbuf = packed (B,C)
        cast_pad_kernel<<<(128 * DINNER / 4) / 256, 256, 0, stream>>>(
            W_x + (size_t)i * 64 * DINNER, wxb, 64, DINNER / 4, 128 * DINNER / 4);
        gemm_mfma<MEPI_SPLIT><<<dim3(1, MROWS / 128), 256, 0, stream>>>(
            xcb, DINNER, wxb, xdt, 0, nullptr, 0, bcbuf, 0, 64, DINNER, nullptr, nullptr);
        // W_dt (f32, K=32, softplus): dtb (bf16)
        gemm_f32_sp<<<dim3(DINNER / 64, MROWS / 64), 256, 0, stream>>>(
            xdt, 32, W_dt + (size_t)i * DINNER * DTRANK, dtb, DINNER, DINNER, DTRANK,
            b_dt + (size_t)i * DINNER);
        scan_kernel<<<(32 * DINNER) / 16, 256, 0, stream>>>(
            dtb, bcbuf, xcb, xzb + DINNER, A_log + (size_t)i * DINNER * DSTATE,
            D_p + (size_t)i * DINNER, yb);
        // W_out: xb = bf16(yb @ W_out^T)
        cast_bf16_kernel<<<(DMODEL * DINNER / 4) / 256, 256, 0, stream>>>(
            W_out + (size_t)i * DMODEL * DINNER, wbuf, DMODEL * DINNER / 4);
        gemm_mfma<MEPI_BF16><<<dim3(DMODEL / 128, MROWS / 128), 256, 0, stream>>>(
            yb, DINNER, wbuf, nullptr, 0, xb, DMODEL, nullptr, 0, DMODEL, DINNER, nullptr, nullptr);
    }

    cast_bf16_kernel<<<(DMODEL * DMODEL / 4) / 256, 256, 0, stream>>>(ffn_W1, wbuf, DMODEL * DMODEL / 4);
    gemm_mfma<MEPI_RELUF><<<dim3(DMODEL / 128, MROWS / 128), 256, 0, stream>>>(
        xb, DMODEL, wbuf, hbuf, DMODEL, nullptr, 0, nullptr, 0, DMODEL, DMODEL, ffn_b1, nullptr);
    ffn2_kernel<<<MROWS * 32 / 256, 256, 0, stream>>>(hbuf, ffn_W2, ffn_b2, out);
}

// Round 6
// 1324.818 us; speedup vs baseline: 1.0999x; 1.0999x over previous
//
#include <hip/hip_runtime.h>
#include <hip/hip_bf16.h>
#include <cstdint>
#include <cstddef>

#define HIST    256
#define DMODEL  512
#define DINNER  1024
#define DSTATE  16
#define DTRANK  32
#define OBSDIM  4096
#define OBSOUT  448
#define ADIM    64
#define NLAYERS 4
#define MROWS   8192   // BATCH*HIST

typedef __bf16  bf16x8 __attribute__((ext_vector_type(8)));
typedef float   f32x4  __attribute__((ext_vector_type(4)));

enum { MEPI_TOK = 0, MEPI_BF16 = 1, MEPI_SPLIT = 2, MEPI_RELUB = 3 };

__device__ __forceinline__ float siluf(float x) { return x / (1.f + __expf(-x)); }
__device__ __forceinline__ float softplusf(float x) {
    return fmaxf(x, 0.f) + log1pf(__expf(-fabsf(x)));
}
__device__ __forceinline__ float bflo(unsigned u) { return __uint_as_float(u << 16); }
__device__ __forceinline__ float bfhi(unsigned u) { return __uint_as_float(u & 0xffff0000u); }

// ---------------------------------------------------------------------------
// bf16 MFMA GEMM, 128x128 tile, BK=32 (m97-style global_load_lds staging).
// MEPI_SPLIT epilogue (W_x): n<32 -> Cf[m*32+n] = v (dt_pre f32);
//   n in [32,64): (B,C) written PAIR-INTERLEAVED across adjacent m rows as bf16:
//   Cb[(m>>1)*64 + state*4 + (m&1)*2 + sel], state=n&15, sel=(n>>4)&1 (0=B,1=C).
template<int EPI>
__global__ __launch_bounds__(256)
void gemm_mfma(const __hip_bfloat16* __restrict__ A, int lda,
               const __hip_bfloat16* __restrict__ W,
               float* __restrict__ Cf, int ldc,
               __hip_bfloat16* __restrict__ Cb, int ldcb,
               int coff, int N, int K,
               const float* __restrict__ bias, const float* __restrict__ pos)
{
    __shared__ __hip_bfloat16 Asm[128 * 32];
    __shared__ __hip_bfloat16 Bsm[128 * 32];
    const int tid  = threadIdx.x;
    const int lane = tid & 63;
    const int wv   = tid >> 6;
    const int m0   = blockIdx.y * 128;
    const int n0   = blockIdx.x * 128;
    const int wm   = (wv >> 1) << 6;
    const int wn   = (wv & 1) << 6;
    const int sr   = lane >> 2;
    const int sc   = (lane & 3) << 3;
    const int quad = lane >> 4;
    const int c16  = lane & 15;

    f32x4 acc[4][4] = {};
    const __hip_bfloat16* aptr = A + (size_t)(m0 + wv * 16 + sr) * lda + sc;
    const __hip_bfloat16* bptr = W + (size_t)(n0 + wv * 16 + sr) * K + sc;
    __hip_bfloat16* asml = Asm + wv * 16 * 32;
    __hip_bfloat16* bsml = Bsm + wv * 16 * 32;

    for (int k0 = 0; k0 < K; k0 += 32) {
        __syncthreads();
        __builtin_amdgcn_global_load_lds(
            (const __attribute__((address_space(1))) void*)(aptr + k0),
            (__attribute__((address_space(3))) void*)(asml), 16, 0, 0);
        __builtin_amdgcn_global_load_lds(
            (const __attribute__((address_space(1))) void*)(aptr + (size_t)64 * lda + k0),
            (__attribute__((address_space(3))) void*)(asml + 64 * 32), 16, 0, 0);
        __builtin_amdgcn_global_load_lds(
            (const __attribute__((address_space(1))) void*)(bptr + k0),
            (__attribute__((address_space(3))) void*)(bsml), 16, 0, 0);
        __builtin_amdgcn_global_load_lds(
            (const __attribute__((address_space(1))) void*)(bptr + (size_t)64 * K + k0),
            (__attribute__((address_space(3))) void*)(bsml + 64 * 32), 16, 0, 0);
        __syncthreads();

        bf16x8 af[4], bfr[4];
        #pragma unroll
        for (int i = 0; i < 4; ++i) {
            af[i]  = *(const bf16x8*)(Asm + (wm + i * 16 + c16) * 32 + quad * 8);
            bfr[i] = *(const bf16x8*)(Bsm + (wn + i * 16 + c16) * 32 + quad * 8);
        }
        #pragma unroll
        for (int i = 0; i < 4; ++i)
            #pragma unroll
            for (int j = 0; j < 4; ++j)
                acc[i][j] = __builtin_amdgcn_mfma_f32_16x16x32_bf16(af[i], bfr[j], acc[i][j], 0, 0, 0);
    }

    #pragma unroll
    for (int i = 0; i < 4; ++i) {
        const int mbase = m0 + wm + i * 16 + quad * 4;
        #pragma unroll
        for (int j = 0; j < 4; ++j) {
            const int n = n0 + wn + j * 16 + c16;
            if (n < N) {
                #pragma unroll
                for (int r = 0; r < 4; ++r) {
                    const size_t m = mbase + r;
                    float v = acc[i][j][r];
                    if (EPI == MEPI_TOK) {
                        v += bias[n] + pos[(m & (HIST - 1)) * DMODEL + coff + n];
                        Cb[m * ldcb + coff + n] = __float2bfloat16(v);
                    } else if (EPI == MEPI_BF16) {
                        Cb[m * ldcb + n] = __float2bfloat16(v);
                    } else if (EPI == MEPI_SPLIT) {
                        if (n < DTRANK) Cf[m * 32 + n] = v;
                        else Cb[(m >> 1) * 64 + (n & 15) * 4 + (m & 1) * 2 + ((n >> 4) & 1)]
                                 = __float2bfloat16(v);
                    } else { // MEPI_RELUB
                        Cb[m * ldcb + n] = __float2bfloat16(fmaxf(v + bias[n], 0.f));
                    }
                }
            }
        }
    }
}

// ---------------------------------------------------------------------------
// f32 GEMM for W_dt (K=32): dtb = bf16(softplus(xdt @ W_dt^T + b_dt))
__global__ __launch_bounds__(256)
void gemm_f32_sp(const float* __restrict__ A, int lda,
                 const float* __restrict__ W,
                 __hip_bfloat16* __restrict__ C, int ldc,
                 int N, int K, const float* __restrict__ bias)
{
    __shared__ float As[32][68];
    __shared__ float Ws[32][68];
    const int tid = threadIdx.x;
    const int tx = tid & 15, ty = tid >> 4;
    const int m0 = blockIdx.y * 64;
    const int n0 = blockIdx.x * 64;
    const int lr = tid >> 3;
    const int lc = (tid & 7) << 2;
    float acc[4][4] = {};
    for (int k0 = 0; k0 < K; k0 += 32) {
        const float4 a0 = *(const float4*)(A + (size_t)(m0 + lr) * lda + k0 + lc);
        const float4 a1 = *(const float4*)(A + (size_t)(m0 + lr + 32) * lda + k0 + lc);
        const float4 b0 = *(const float4*)(W + (size_t)(n0 + lr) * K + k0 + lc);
        const float4 b1 = *(const float4*)(W + (size_t)(n0 + lr + 32) * K + k0 + lc);
        __syncthreads();
        As[lc+0][lr] = a0.x; As[lc+1][lr] = a0.y; As[lc+2][lr] = a0.z; As[lc+3][lr] = a0.w;
        As[lc+0][lr+32] = a1.x; As[lc+1][lr+32] = a1.y; As[lc+2][lr+32] = a1.z; As[lc+3][lr+32] = a1.w;
        Ws[lc+0][lr] = b0.x; Ws[lc+1][lr] = b0.y; Ws[lc+2][lr] = b0.z; Ws[lc+3][lr] = b0.w;
        Ws[lc+0][lr+32] = b1.x; Ws[lc+1][lr+32] = b1.y; Ws[lc+2][lr+32] = b1.z; Ws[lc+3][lr+32] = b1.w;
        __syncthreads();
        #pragma unroll
        for (int k = 0; k < 32; ++k) {
            const float4 a4 = *(const float4*)&As[k][ty << 2];
            const float4 b4 = *(const float4*)&Ws[k][tx << 2];
            const float a[4] = {a4.x, a4.y, a4.z, a4.w};
            const float b[4] = {b4.x, b4.y, b4.z, b4.w};
            #pragma unroll
            for (int i = 0; i < 4; ++i)
                #pragma unroll
                for (int j = 0; j < 4; ++j)
                    acc[i][j] = fmaf(a[i], b[j], acc[i][j]);
        }
    }
    const int mb = m0 + (ty << 2);
    const int nb = n0 + (tx << 2);
    #pragma unroll
    for (int i = 0; i < 4; ++i) {
        const size_t m = mb + i;
        #pragma unroll
        for (int j = 0; j < 4; ++j) {
            const int n = nb + j;
            C[m * ldc + n] = __float2bfloat16(softplusf(acc[i][j] + bias[n]));
        }
    }
}

// ---------------------------------------------------------------------------
__global__ __launch_bounds__(256)
void cast_bf16_kernel(const float* __restrict__ src, __hip_bfloat16* __restrict__ dst, int n4)
{
    const int i = blockIdx.x * 256 + threadIdx.x;
    if (i >= n4) return;
    const float4 v = ((const float4*)src)[i];
    union { __hip_bfloat16 h[4]; short4 s; } o;
    o.h[0] = __float2bfloat16(v.x); o.h[1] = __float2bfloat16(v.y);
    o.h[2] = __float2bfloat16(v.z); o.h[3] = __float2bfloat16(v.w);
    ((short4*)dst)[i] = o.s;
}

__global__ __launch_bounds__(256)
void cast_pad_kernel(const float* __restrict__ src, __hip_bfloat16* __restrict__ dst,
                     int nrows, int K4, int total4)
{
    const int i = blockIdx.x * 256 + threadIdx.x;
    if (i >= total4) return;
    const int row = i / K4;
    float4 v = make_float4(0.f, 0.f, 0.f, 0.f);
    if (row < nrows) v = ((const float4*)src)[i];
    union { __hip_bfloat16 h[4]; short4 s; } o;
    o.h[0] = __float2bfloat16(v.x); o.h[1] = __float2bfloat16(v.y);
    o.h[2] = __float2bfloat16(v.z); o.h[3] = __float2bfloat16(v.w);
    ((short4*)dst)[i] = o.s;
}

__global__ __launch_bounds__(256)
void embed_kernel(const int* __restrict__ actions, const float* __restrict__ act_emb,
                  const float* __restrict__ pos_emb, __hip_bfloat16* __restrict__ xb)
{
    const int idx = blockIdx.x * 256 + threadIdx.x;   // MROWS*64
    const int e = idx & 63;
    const int m = idx >> 6;
    const int l = m & (HIST - 1);
    const int b = m >> 8;
    float v = pos_emb[l * DMODEL + e];
    if (l > 0) {
        const int a = actions[b * HIST + l - 1];
        v += act_emb[a * ADIM + e];
    }
    xb[(size_t)m * DMODEL + e] = __float2bfloat16(v);
}

// xcb[m,d] = bf16(silu(conv_b[d] + sum_k conv_w[d,k]*xi[l-3+k, d]))
__global__ __launch_bounds__(256)
void conv_silu_kernel(const __hip_bfloat16* __restrict__ xzb, const float* __restrict__ cw,
                      const float* __restrict__ cb, __hip_bfloat16* __restrict__ xcb)
{
    const int idx = blockIdx.x * 256 + threadIdx.x;   // MROWS*DINNER
    const int d = idx & (DINNER - 1);
    const int m = idx >> 10;
    const int l = m & (HIST - 1);
    const float4 w = ((const float4*)cw)[d];
    const __hip_bfloat16* basep = xzb + (size_t)m * (2 * DINNER) + d;
    float acc = cb[d] + w.w * __bfloat162float(basep[0]);
    if (l >= 1) acc = fmaf(w.z, __bfloat162float(basep[-2 * DINNER]), acc);
    if (l >= 2) acc = fmaf(w.y, __bfloat162float(basep[-4 * DINNER]), acc);
    if (l >= 3) acc = fmaf(w.x, __bfloat162float(basep[-6 * DINNER]), acc);
    xcb[idx] = __float2bfloat16(siluf(acc));
}

// ---------------------------------------------------------------------------
// Selective scan v3: FULL LDS staging. Block = 256 threads = 16 channel groups
// (16 consecutive d of one batch b) x 16 state lanes. At block start, ONE
// coalesced burst stages the block's whole 256-step working set into LDS:
//   sbc2: (B,C) pairs, 2 steps per 8B entry (written pre-interleaved by W_x)
//   sdx2: (dt,xc) pairs, 2 steps per 8B entry (interleaved during staging)
//   sz  : z values (epilogue only)
// Then 256 scan steps run purely from LDS: 2x ds_read_b64 per 2 steps +
// DPP butterfly reduction. No per-step global loads -> no exposed HBM/L2 latency.
__device__ __forceinline__ float dpp_add(float x, const int ctrl) {
    switch (ctrl) {
    case 0xB1:  return x + __int_as_float(__builtin_amdgcn_update_dpp(0, __float_as_int(x), 0xB1, 0xF, 0xF, true));
    case 0x4E:  return x + __int_as_float(__builtin_amdgcn_update_dpp(0, __float_as_int(x), 0x4E, 0xF, 0xF, true));
    case 0x141: return x + __int_as_float(__builtin_amdgcn_update_dpp(0, __float_as_int(x), 0x141, 0xF, 0xF, true));
    default:    return x + __int_as_float(__builtin_amdgcn_update_dpp(0, __float_as_int(x), 0x140, 0xF, 0xF, true));
    }
}

__global__ __launch_bounds__(256)
void scan_kernel(const __hip_bfloat16* __restrict__ dtb, const __hip_bfloat16* __restrict__ bcb,
                 const __hip_bfloat16* __restrict__ xcb, const __hip_bfloat16* __restrict__ zb,
                 const float* __restrict__ A_log, const float* __restrict__ D_p,
                 __hip_bfloat16* __restrict__ yb)
{
    __shared__ unsigned sdx2[128][32];   // [pair-row][g*2+{0,1}]: dt0|xc0, dt1|xc1  (16 KB)
    __shared__ unsigned sbc2[128][32];   // [pair-row][n*2+{0,1}]: B0|C0, B1|C1      (16 KB)
    __shared__ unsigned short sz[256][16]; // [l][g]                                  (8 KB)
    const int tid = threadIdx.x;
    const int n   = tid & 15;
    const int g   = tid >> 4;            // 0..15 channel group
    const int c0  = blockIdx.x * 16;
    const int b   = c0 >> 10;
    const int d0  = c0 & (DINNER - 1);
    const int d   = d0 + g;
    const size_t row0 = (size_t)b * HIST;

    // --- stage bc: flat 16 KB contiguous copy ---
    {
        const uint4* src = (const uint4*)((const unsigned short*)bcb + row0 * 32);
        uint4* dst = (uint4*)&sbc2[0][0];
        #pragma unroll
        for (int i = 0; i < 4; ++i) dst[tid + i * 256] = src[tid + i * 256];
    }
    // --- stage dt/xc interleaved: thread t -> pair-row P=t>>1, half=t&1 (g' 0..7) ---
    {
        const int P = tid >> 1, half = tid & 1;
        const size_t m0r = row0 + 2 * P, m1r = m0r + 1;
        const unsigned short* dtu = (const unsigned short*)dtb;
        const unsigned short* xcu = (const unsigned short*)xcb;
        union { uint4 u; unsigned short s[8]; } D0, D1, X0, X1;
        D0.u = *(const uint4*)(dtu + m0r * DINNER + d0 + half * 8);
        D1.u = *(const uint4*)(dtu + m1r * DINNER + d0 + half * 8);
        X0.u = *(const uint4*)(xcu + m0r * DINNER + d0 + half * 8);
        X1.u = *(const uint4*)(xcu + m1r * DINNER + d0 + half * 8);
        #pragma unroll
        for (int gp = 0; gp < 8; ++gp) {
            sdx2[P][(half * 8 + gp) * 2]     = (unsigned)D0.s[gp] | ((unsigned)X0.s[gp] << 16);
            sdx2[P][(half * 8 + gp) * 2 + 1] = (unsigned)D1.s[gp] | ((unsigned)X1.s[gp] << 16);
        }
    }
    // --- stage z: thread t -> row l=t>>1, half=t&1; 2 iterations ---
    {
        const int l = tid >> 1, half = tid & 1;
        const unsigned short* zu = (const unsigned short*)zb;
        #pragma unroll
        for (int i = 0; i < 2; ++i) {
            const int ll = l + i * 128;
            *(uint4*)&sz[ll][half * 8] =
                *(const uint4*)(zu + (row0 + ll) * 2 * DINNER + d0 + half * 8);
        }
    }
    __syncthreads();

    const float A  = -__expf(A_log[d * DSTATE + n]);
    const float Dp = D_p[d];
    float h = 0.f;

    for (int l0 = 0; l0 < HIST; l0 += 16) {
        float yreg = 0.f;
        #pragma unroll
        for (int jp = 0; jp < 8; ++jp) {
            const int P = (l0 >> 1) + jp;
            const uint2 q  = *(const uint2*)&sdx2[P][g * 2];
            const uint2 r2 = *(const uint2*)&sbc2[P][n * 2];
            // step 2*jp
            {
                const float dt = bflo(q.x), xc = bfhi(q.x);
                const float Bv = bflo(r2.x), Cv = bfhi(r2.x);
                const float dA = __expf(dt * A);
                h = fmaf(dA, h, dt * xc * Bv);
                float ctr = h * Cv;
                ctr = dpp_add(ctr, 0xB1);
                ctr = dpp_add(ctr, 0x4E);
                ctr = dpp_add(ctr, 0x141);
                ctr = dpp_add(ctr, 0x140);
                if (n == 2 * jp) yreg = ctr;
            }
            // step 2*jp+1
            {
                const float dt = bflo(q.y), xc = bfhi(q.y);
                const float Bv = bflo(r2.y), Cv = bfhi(r2.y);
                const float dA = __expf(dt * A);
                h = fmaf(dA, h, dt * xc * Bv);
                float ctr = h * Cv;
                ctr = dpp_add(ctr, 0xB1);
                ctr = dpp_add(ctr, 0x4E);
                ctr = dpp_add(ctr, 0x141);
                ctr = dpp_add(ctr, 0x140);
                if (n == 2 * jp + 1) yreg = ctr;
            }
        }
        // epilogue for rows l0..l0+15: lane n owns row l0+n
        const int lr = l0 + n;
        const unsigned short xcu16 =
            ((const unsigned short*)sdx2)[(lr >> 1) * 64 + g * 4 + 1 + 2 * (lr & 1)];
        const float xce = bflo((unsigned)xcu16) ;   // stored as low? no: xc is HIGH half
        const float xcf = __uint_as_float(((unsigned)xcu16) << 16);
        (void)xce;
        const float ze = __uint_as_float(((unsigned)sz[lr][g]) << 16);
        yb[(row0 + lr) * DINNER + d] =
            __float2bfloat16((yreg + xcf * Dp) * siluf(ze));
    }
}

// out[m,n] = b2[n] + sum_k h[m,k]*W2[n,k]  (h in bf16)
__global__ __launch_bounds__(256)
void ffn2_kernel(const __hip_bfloat16* __restrict__ h, const float* __restrict__ W2,
                 const float* __restrict__ b2, float* __restrict__ out)
{
    const int idx = blockIdx.x * 256 + threadIdx.x;   // MROWS*32
    const int n = idx & 31;
    const int m = idx >> 5;
    if (n >= 18) return;
    const unsigned short* hr = (const unsigned short*)(h + (size_t)m * DMODEL);
    const float* wr = W2 + (size_t)n * DMODEL;
    float acc = b2[n];
    for (int k = 0; k < DMODEL; k += 8) {
        const uint4 hv = *(const uint4*)(hr + k);
        const float4 w0 = *(const float4*)(wr + k);
        const float4 w1 = *(const float4*)(wr + k + 4);
        acc = fmaf(bflo(hv.x), w0.x, acc);
        acc = fmaf(bfhi(hv.x), w0.y, acc);
        acc = fmaf(bflo(hv.y), w0.z, acc);
        acc = fmaf(bfhi(hv.y), w0.w, acc);
        acc = fmaf(bflo(hv.z), w1.x, acc);
        acc = fmaf(bfhi(hv.z), w1.y, acc);
        acc = fmaf(bflo(hv.w), w1.z, acc);
        acc = fmaf(bfhi(hv.w), w1.w, acc);
    }
    out[(size_t)m * 18 + n] = acc;
}

extern "C" void kernel_launch(void* const* d_in, const int* in_sizes, int n_in,
                              void* d_out, int out_size, void* d_ws, size_t ws_size,
                              hipStream_t stream)
{
    const float* obss    = (const float*)d_in[0];
    const int*   actions = (const int*)  d_in[1];
    const float* obs_W   = (const float*)d_in[2];
    const float* obs_b   = (const float*)d_in[3];
    const float* act_emb = (const float*)d_in[4];
    const float* pos_emb = (const float*)d_in[5];
    const float* W_in    = (const float*)d_in[6];
    const float* conv_w  = (const float*)d_in[7];
    const float* conv_b  = (const float*)d_in[8];
    const float* W_x     = (const float*)d_in[9];
    const float* W_dt    = (const float*)d_in[10];
    const float* b_dt    = (const float*)d_in[11];
    const float* A_log   = (const float*)d_in[12];
    const float* D_p     = (const float*)d_in[13];
    const float* W_out   = (const float*)d_in[14];
    const float* ffn_W1  = (const float*)d_in[15];
    const float* ffn_b1  = (const float*)d_in[16];
    const float* ffn_W2  = (const float*)d_in[17];
    const float* ffn_b2  = (const float*)d_in[18];
    float* out = (float*)d_out;

    // Workspace (MiB offsets, lifetime-aliased):
    //  0-8    xb   (bf16 M x 512)        8-40   xzb (bf16 M x 2048: xi|z)
    //  40-56  xcb  (bf16 M x 1024)       56-72  dtb (bf16 M x 1024)
    //  88-104 yb   (bf16 M x 1024)       104-105 xdt (f32 M x 32)
    //  105-106 bcb (bf16 pair-interleaved M x 32)   106-110 wbuf (bf16 weights)
    //  110-110.25 wxb (bf16 128 x 1024)
    //  prologue: obssb @8-72;  epilogue: hbuf (bf16) @8-16
    const size_t MiB = 1024 * 1024;
    char* base = (char*)d_ws;
    __hip_bfloat16* xb    = (__hip_bfloat16*)(base);
    __hip_bfloat16* xzb   = (__hip_bfloat16*)(base + 8 * MiB);
    __hip_bfloat16* xcb   = (__hip_bfloat16*)(base + 40 * MiB);
    __hip_bfloat16* dtb   = (__hip_bfloat16*)(base + 56 * MiB);
    __hip_bfloat16* yb    = (__hip_bfloat16*)(base + 88 * MiB);
    float*          xdt   = (float*)(base + 104 * MiB);
    __hip_bfloat16* bcb   = (__hip_bfloat16*)(base + 105 * MiB);
    __hip_bfloat16* wbuf  = (__hip_bfloat16*)(base + 106 * MiB);
    __hip_bfloat16* wxb   = (__hip_bfloat16*)(base + 110 * MiB);
    __hip_bfloat16* obssb = (__hip_bfloat16*)(base + 8 * MiB);
    __hip_bfloat16* hbuf  = (__hip_bfloat16*)(base + 8 * MiB);

    // --- prologue ---
    cast_bf16_kernel<<<(MROWS * OBSDIM / 4) / 256, 256, 0, stream>>>(obss, obssb, MROWS * OBSDIM / 4);
    cast_pad_kernel<<<(512 * OBSDIM / 4) / 256, 256, 0, stream>>>(obs_W, wbuf, OBSOUT, OBSDIM / 4, 512 * OBSDIM / 4);
    embed_kernel<<<MROWS * ADIM / 256, 256, 0, stream>>>(actions, act_emb, pos_emb, xb);
    gemm_mfma<MEPI_TOK><<<dim3(4, MROWS / 128), 256, 0, stream>>>(
        obssb, OBSDIM, wbuf, nullptr, 0, xb, DMODEL, ADIM, OBSOUT, OBSDIM, obs_b, pos_emb);

    for (int i = 0; i < NLAYERS; ++i) {
        // W_in: xzb = bf16(xb @ W_in^T), ld 2048 (xi | z)
        cast_bf16_kernel<<<(2 * DINNER * DMODEL / 4) / 256, 256, 0, stream>>>(
            W_in + (size_t)i * 2 * DINNER * DMODEL, wbuf, 2 * DINNER * DMODEL / 4);
        gemm_mfma<MEPI_BF16><<<dim3(2 * DINNER / 128, MROWS / 128), 256, 0, stream>>>(
            xb, DMODEL, wbuf, nullptr, 0, xzb, 2 * DINNER, 0, 2 * DINNER, DMODEL,
            nullptr, nullptr);
        conv_silu_kernel<<<MROWS * DINNER / 256, 256, 0, stream>>>(
            xzb, conv_w + (size_t)i * DINNER * 4, conv_b + (size_t)i * DINNER, xcb);
        // W_x (mfma, split): xdt = xcb @ W_x^T[:32] (f32), bcb = pair-interleaved bf16 (B,C)
        cast_pad_kernel<<<(128 * DINNER / 4) / 256, 256, 0, stream>>>(
            W_x + (size_t)i * 64 * DINNER, wxb, 64, DINNER / 4, 128 * DINNER / 4);
        gemm_mfma<MEPI_SPLIT><<<dim3(1, MROWS / 128), 256, 0, stream>>>(
            xcb, DINNER, wxb, xdt, 0, bcb, 0, 0, 64, DINNER, nullptr, nullptr);
        // W_dt (f32, K=32, softplus): dtb (bf16)
        gemm_f32_sp<<<dim3(DINNER / 64, MROWS / 64), 256, 0, stream>>>(
            xdt, 32, W_dt + (size_t)i * DINNER * DTRANK, dtb, DINNER, DINNER, DTRANK,
            b_dt + (size_t)i * DINNER);
        scan_kernel<<<(32 * DINNER) / 16, 256, 0, stream>>>(
            dtb, bcb, xcb, xzb + DINNER, A_log + (size_t)i * DINNER * DSTATE,
            D_p + (size_t)i * DINNER, yb);
        // W_out: xb = bf16(yb @ W_out^T)
        cast_bf16_kernel<<<(DMODEL * DINNER / 4) / 256, 256, 0, stream>>>(
            W_out + (size_t)i * DMODEL * DINNER, wbuf, DMODEL * DINNER / 4);
        gemm_mfma<MEPI_BF16><<<dim3(DMODEL / 128, MROWS / 128), 256, 0, stream>>>(
            yb, DINNER, wbuf, nullptr, 0, xb, DMODEL, 0, DMODEL, DINNER, nullptr, nullptr);
    }

    cast_bf16_kernel<<<(DMODEL * DMODEL / 4) / 256, 256, 0, stream>>>(ffn_W1, wbuf, DMODEL * DMODEL / 4);
    gemm_mfma<MEPI_RELUB><<<dim3(DMODEL / 128, MROWS / 128), 256, 0, stream>>>(
        xb, DMODEL, wbuf, nullptr, 0, hbuf, DMODEL, 0, DMODEL, DMODEL, ffn_b1, nullptr);
    ffn2_kernel<<<MROWS * 32 / 256, 256, 0, stream>>>(hbuf, ffn_W2, ffn_b2, out);
}

// Round 7
// 1281.762 us; speedup vs baseline: 1.1369x; 1.0336x over previous
//
#include <hip/hip_runtime.h>
#include <hip/hip_bf16.h>
#include <cstdint>
#include <cstddef>

#define HIST    256
#define DMODEL  512
#define DINNER  1024
#define DSTATE  16
#define DTRANK  32
#define OBSDIM  4096
#define OBSOUT  448
#define ADIM    64
#define NLAYERS 4
#define MROWS   8192   // BATCH*HIST

typedef __bf16  bf16x8 __attribute__((ext_vector_type(8)));
typedef float   f32x4  __attribute__((ext_vector_type(4)));

enum { MEPI_TOK = 0, MEPI_BF16 = 1, MEPI_SPLIT = 2, MEPI_RELUB = 3 };

__device__ __forceinline__ float siluf(float x) { return x / (1.f + __expf(-x)); }
__device__ __forceinline__ float softplusf(float x) {
    return fmaxf(x, 0.f) + log1pf(__expf(-fabsf(x)));
}
__device__ __forceinline__ float bflo(unsigned u) { return __uint_as_float(u << 16); }
__device__ __forceinline__ float bfhi(unsigned u) { return __uint_as_float(u & 0xffff0000u); }

// ---------------------------------------------------------------------------
// bf16 MFMA GEMM, 128x128 tile, BK=32, double-buffered LDS, XCD-swizzled grid.
// Grid is 1-D flat = nbn*nbm blocks (nbm % 8 == 0). Decode: xcd = bid&7 owns a
// contiguous stripe of nbm/8 m-blocks and iterates its n-blocks fastest ->
// W and the A-stripe stay resident in that XCD's 4 MiB L2.
template<int EPI>
__global__ __launch_bounds__(256)
void gemm_mfma(const __hip_bfloat16* __restrict__ A, int lda,
               const __hip_bfloat16* __restrict__ W,
               float* __restrict__ Cf, int ldc,
               __hip_bfloat16* __restrict__ Cb, int ldcb,
               int coff, int N, int K, int nbn,
               const float* __restrict__ bias, const float* __restrict__ pos)
{
    __shared__ __hip_bfloat16 Asm[2][128 * 32];
    __shared__ __hip_bfloat16 Bsm[2][128 * 32];
    const int bid = blockIdx.x;
    const int xcd = bid & 7;
    const int s   = bid >> 3;
    const int n_blk = s % nbn;
    const int m_blk = xcd * ((int)(gridDim.x >> 3) / nbn) + s / nbn;
    const int m0 = m_blk * 128;
    const int n0 = n_blk * 128;

    const int tid  = threadIdx.x;
    const int lane = tid & 63;
    const int wv   = tid >> 6;
    const int wm   = (wv >> 1) << 6;
    const int wn   = (wv & 1) << 6;
    const int sr   = lane >> 2;
    const int sc   = (lane & 3) << 3;
    const int quad = lane >> 4;
    const int c16  = lane & 15;

    f32x4 acc[4][4] = {};
    const __hip_bfloat16* aptr = A + (size_t)(m0 + wv * 16 + sr) * lda + sc;
    const __hip_bfloat16* bptr = W + (size_t)(n0 + wv * 16 + sr) * K + sc;

#define STAGE(K0, BUF) { \
    __hip_bfloat16* asml = Asm[BUF] + wv * 16 * 32; \
    __hip_bfloat16* bsml = Bsm[BUF] + wv * 16 * 32; \
    __builtin_amdgcn_global_load_lds( \
        (const __attribute__((address_space(1))) void*)(aptr + (K0)), \
        (__attribute__((address_space(3))) void*)(asml), 16, 0, 0); \
    __builtin_amdgcn_global_load_lds( \
        (const __attribute__((address_space(1))) void*)(aptr + (size_t)64 * lda + (K0)), \
        (__attribute__((address_space(3))) void*)(asml + 64 * 32), 16, 0, 0); \
    __builtin_amdgcn_global_load_lds( \
        (const __attribute__((address_space(1))) void*)(bptr + (K0)), \
        (__attribute__((address_space(3))) void*)(bsml), 16, 0, 0); \
    __builtin_amdgcn_global_load_lds( \
        (const __attribute__((address_space(1))) void*)(bptr + (size_t)64 * K + (K0)), \
        (__attribute__((address_space(3))) void*)(bsml + 64 * 32), 16, 0, 0); \
    }

    STAGE(0, 0)
    __syncthreads();
    int cur = 0;
    for (int k0 = 0; k0 < K; k0 += 32) {
        if (k0 + 32 < K) STAGE(k0 + 32, cur ^ 1)

        bf16x8 af[4], bfr[4];
        #pragma unroll
        for (int i = 0; i < 4; ++i) {
            af[i]  = *(const bf16x8*)(Asm[cur] + (wm + i * 16 + c16) * 32 + quad * 8);
            bfr[i] = *(const bf16x8*)(Bsm[cur] + (wn + i * 16 + c16) * 32 + quad * 8);
        }
        #pragma unroll
        for (int i = 0; i < 4; ++i)
            #pragma unroll
            for (int j = 0; j < 4; ++j)
                acc[i][j] = __builtin_amdgcn_mfma_f32_16x16x32_bf16(af[i], bfr[j], acc[i][j], 0, 0, 0);

        __syncthreads();   // drains next-tile loads (issued before compute) + guards buffer reuse
        cur ^= 1;
    }
#undef STAGE

    #pragma unroll
    for (int i = 0; i < 4; ++i) {
        const int mbase = m0 + wm + i * 16 + quad * 4;
        #pragma unroll
        for (int j = 0; j < 4; ++j) {
            const int n = n0 + wn + j * 16 + c16;
            if (n < N) {
                #pragma unroll
                for (int r = 0; r < 4; ++r) {
                    const size_t m = mbase + r;
                    float v = acc[i][j][r];
                    if (EPI == MEPI_TOK) {
                        v += bias[n] + pos[(m & (HIST - 1)) * DMODEL + coff + n];
                        Cb[m * ldcb + coff + n] = __float2bfloat16(v);
                    } else if (EPI == MEPI_BF16) {
                        Cb[m * ldcb + n] = __float2bfloat16(v);
                    } else if (EPI == MEPI_SPLIT) {
                        if (n < DTRANK) Cf[m * 32 + n] = v;
                        else Cb[(m >> 1) * 64 + (n & 15) * 4 + (m & 1) * 2 + ((n >> 4) & 1)]
                                 = __float2bfloat16(v);
                    } else { // MEPI_RELUB
                        Cb[m * ldcb + n] = __float2bfloat16(fmaxf(v + bias[n], 0.f));
                    }
                }
            }
        }
    }
}

// ---------------------------------------------------------------------------
// f32 GEMM for W_dt (K=32): dtb = bf16(softplus(xdt @ W_dt^T + b_dt))
__global__ __launch_bounds__(256)
void gemm_f32_sp(const float* __restrict__ A, int lda,
                 const float* __restrict__ W,
                 __hip_bfloat16* __restrict__ C, int ldc,
                 int N, int K, const float* __restrict__ bias)
{
    __shared__ float As[32][68];
    __shared__ float Ws[32][68];
    const int tid = threadIdx.x;
    const int tx = tid & 15, ty = tid >> 4;
    const int m0 = blockIdx.y * 64;
    const int n0 = blockIdx.x * 64;
    const int lr = tid >> 3;
    const int lc = (tid & 7) << 2;
    float acc[4][4] = {};
    for (int k0 = 0; k0 < K; k0 += 32) {
        const float4 a0 = *(const float4*)(A + (size_t)(m0 + lr) * lda + k0 + lc);
        const float4 a1 = *(const float4*)(A + (size_t)(m0 + lr + 32) * lda + k0 + lc);
        const float4 b0 = *(const float4*)(W + (size_t)(n0 + lr) * K + k0 + lc);
        const float4 b1 = *(const float4*)(W + (size_t)(n0 + lr + 32) * K + k0 + lc);
        __syncthreads();
        As[lc+0][lr] = a0.x; As[lc+1][lr] = a0.y; As[lc+2][lr] = a0.z; As[lc+3][lr] = a0.w;
        As[lc+0][lr+32] = a1.x; As[lc+1][lr+32] = a1.y; As[lc+2][lr+32] = a1.z; As[lc+3][lr+32] = a1.w;
        Ws[lc+0][lr] = b0.x; Ws[lc+1][lr] = b0.y; Ws[lc+2][lr] = b0.z; Ws[lc+3][lr] = b0.w;
        Ws[lc+0][lr+32] = b1.x; Ws[lc+1][lr+32] = b1.y; Ws[lc+2][lr+32] = b1.z; Ws[lc+3][lr+32] = b1.w;
        __syncthreads();
        #pragma unroll
        for (int k = 0; k < 32; ++k) {
            const float4 a4 = *(const float4*)&As[k][ty << 2];
            const float4 b4 = *(const float4*)&Ws[k][tx << 2];
            const float a[4] = {a4.x, a4.y, a4.z, a4.w};
            const float b[4] = {b4.x, b4.y, b4.z, b4.w};
            #pragma unroll
            for (int i = 0; i < 4; ++i)
                #pragma unroll
                for (int j = 0; j < 4; ++j)
                    acc[i][j] = fmaf(a[i], b[j], acc[i][j]);
        }
    }
    const int mb = m0 + (ty << 2);
    const int nb = n0 + (tx << 2);
    #pragma unroll
    for (int i = 0; i < 4; ++i) {
        const size_t m = mb + i;
        #pragma unroll
        for (int j = 0; j < 4; ++j) {
            const int n = nb + j;
            C[m * ldc + n] = __float2bfloat16(softplusf(acc[i][j] + bias[n]));
        }
    }
}

// ---------------------------------------------------------------------------
__global__ __launch_bounds__(256)
void cast_bf16_kernel(const float* __restrict__ src, __hip_bfloat16* __restrict__ dst, int n4)
{
    const int i = blockIdx.x * 256 + threadIdx.x;
    if (i >= n4) return;
    const float4 v = ((const float4*)src)[i];
    union { __hip_bfloat16 h[4]; short4 s; } o;
    o.h[0] = __float2bfloat16(v.x); o.h[1] = __float2bfloat16(v.y);
    o.h[2] = __float2bfloat16(v.z); o.h[3] = __float2bfloat16(v.w);
    ((short4*)dst)[i] = o.s;
}

__global__ __launch_bounds__(256)
void cast_pad_kernel(const float* __restrict__ src, __hip_bfloat16* __restrict__ dst,
                     int nrows, int K4, int total4)
{
    const int i = blockIdx.x * 256 + threadIdx.x;
    if (i >= total4) return;
    const int row = i / K4;
    float4 v = make_float4(0.f, 0.f, 0.f, 0.f);
    if (row < nrows) v = ((const float4*)src)[i];
    union { __hip_bfloat16 h[4]; short4 s; } o;
    o.h[0] = __float2bfloat16(v.x); o.h[1] = __float2bfloat16(v.y);
    o.h[2] = __float2bfloat16(v.z); o.h[3] = __float2bfloat16(v.w);
    ((short4*)dst)[i] = o.s;
}

__global__ __launch_bounds__(256)
void embed_kernel(const int* __restrict__ actions, const float* __restrict__ act_emb,
                  const float* __restrict__ pos_emb, __hip_bfloat16* __restrict__ xb)
{
    const int idx = blockIdx.x * 256 + threadIdx.x;   // MROWS*64
    const int e = idx & 63;
    const int m = idx >> 6;
    const int l = m & (HIST - 1);
    const int b = m >> 8;
    float v = pos_emb[l * DMODEL + e];
    if (l > 0) {
        const int a = actions[b * HIST + l - 1];
        v += act_emb[a * ADIM + e];
    }
    xb[(size_t)m * DMODEL + e] = __float2bfloat16(v);
}

// xcb[m,d] = bf16(silu(conv_b[d] + sum_k conv_w[d,k]*xi[l-3+k, d]))
__global__ __launch_bounds__(256)
void conv_silu_kernel(const __hip_bfloat16* __restrict__ xzb, const float* __restrict__ cw,
                      const float* __restrict__ cb, __hip_bfloat16* __restrict__ xcb)
{
    const int idx = blockIdx.x * 256 + threadIdx.x;   // MROWS*DINNER
    const int d = idx & (DINNER - 1);
    const int m = idx >> 10;
    const int l = m & (HIST - 1);
    const float4 w = ((const float4*)cw)[d];
    const __hip_bfloat16* basep = xzb + (size_t)m * (2 * DINNER) + d;
    float acc = cb[d] + w.w * __bfloat162float(basep[0]);
    if (l >= 1) acc = fmaf(w.z, __bfloat162float(basep[-2 * DINNER]), acc);
    if (l >= 2) acc = fmaf(w.y, __bfloat162float(basep[-4 * DINNER]), acc);
    if (l >= 3) acc = fmaf(w.x, __bfloat162float(basep[-6 * DINNER]), acc);
    xcb[idx] = __float2bfloat16(siluf(acc));
}

// ---------------------------------------------------------------------------
// Selective scan v3: full LDS staging (see round-6 notes). Unchanged.
__device__ __forceinline__ float dpp_add(float x, const int ctrl) {
    switch (ctrl) {
    case 0xB1:  return x + __int_as_float(__builtin_amdgcn_update_dpp(0, __float_as_int(x), 0xB1, 0xF, 0xF, true));
    case 0x4E:  return x + __int_as_float(__builtin_amdgcn_update_dpp(0, __float_as_int(x), 0x4E, 0xF, 0xF, true));
    case 0x141: return x + __int_as_float(__builtin_amdgcn_update_dpp(0, __float_as_int(x), 0x141, 0xF, 0xF, true));
    default:    return x + __int_as_float(__builtin_amdgcn_update_dpp(0, __float_as_int(x), 0x140, 0xF, 0xF, true));
    }
}

__global__ __launch_bounds__(256)
void scan_kernel(const __hip_bfloat16* __restrict__ dtb, const __hip_bfloat16* __restrict__ bcb,
                 const __hip_bfloat16* __restrict__ xcb, const __hip_bfloat16* __restrict__ zb,
                 const float* __restrict__ A_log, const float* __restrict__ D_p,
                 __hip_bfloat16* __restrict__ yb)
{
    __shared__ unsigned sdx2[128][32];
    __shared__ unsigned sbc2[128][32];
    __shared__ unsigned short sz[256][16];
    const int tid = threadIdx.x;
    const int n   = tid & 15;
    const int g   = tid >> 4;
    const int c0  = blockIdx.x * 16;
    const int b   = c0 >> 10;
    const int d0  = c0 & (DINNER - 1);
    const int d   = d0 + g;
    const size_t row0 = (size_t)b * HIST;

    {
        const uint4* src = (const uint4*)((const unsigned short*)bcb + row0 * 32);
        uint4* dst = (uint4*)&sbc2[0][0];
        #pragma unroll
        for (int i = 0; i < 4; ++i) dst[tid + i * 256] = src[tid + i * 256];
    }
    {
        const int P = tid >> 1, half = tid & 1;
        const size_t m0r = row0 + 2 * P, m1r = m0r + 1;
        const unsigned short* dtu = (const unsigned short*)dtb;
        const unsigned short* xcu = (const unsigned short*)xcb;
        union { uint4 u; unsigned short s[8]; } D0, D1, X0, X1;
        D0.u = *(const uint4*)(dtu + m0r * DINNER + d0 + half * 8);
        D1.u = *(const uint4*)(dtu + m1r * DINNER + d0 + half * 8);
        X0.u = *(const uint4*)(xcu + m0r * DINNER + d0 + half * 8);
        X1.u = *(const uint4*)(xcu + m1r * DINNER + d0 + half * 8);
        #pragma unroll
        for (int gp = 0; gp < 8; ++gp) {
            sdx2[P][(half * 8 + gp) * 2]     = (unsigned)D0.s[gp] | ((unsigned)X0.s[gp] << 16);
            sdx2[P][(half * 8 + gp) * 2 + 1] = (unsigned)D1.s[gp] | ((unsigned)X1.s[gp] << 16);
        }
    }
    {
        const int l = tid >> 1, half = tid & 1;
        const unsigned short* zu = (const unsigned short*)zb;
        #pragma unroll
        for (int i = 0; i < 2; ++i) {
            const int ll = l + i * 128;
            *(uint4*)&sz[ll][half * 8] =
                *(const uint4*)(zu + (row0 + ll) * 2 * DINNER + d0 + half * 8);
        }
    }
    __syncthreads();

    const float A  = -__expf(A_log[d * DSTATE + n]);
    const float Dp = D_p[d];
    float h = 0.f;

    for (int l0 = 0; l0 < HIST; l0 += 16) {
        float yreg = 0.f;
        #pragma unroll
        for (int jp = 0; jp < 8; ++jp) {
            const int P = (l0 >> 1) + jp;
            const uint2 q  = *(const uint2*)&sdx2[P][g * 2];
            const uint2 r2 = *(const uint2*)&sbc2[P][n * 2];
            {
                const float dt = bflo(q.x), xc = bfhi(q.x);
                const float Bv = bflo(r2.x), Cv = bfhi(r2.x);
                const float dA = __expf(dt * A);
                h = fmaf(dA, h, dt * xc * Bv);
                float ctr = h * Cv;
                ctr = dpp_add(ctr, 0xB1);
                ctr = dpp_add(ctr, 0x4E);
                ctr = dpp_add(ctr, 0x141);
                ctr = dpp_add(ctr, 0x140);
                if (n == 2 * jp) yreg = ctr;
            }
            {
                const float dt = bflo(q.y), xc = bfhi(q.y);
                const float Bv = bflo(r2.y), Cv = bfhi(r2.y);
                const float dA = __expf(dt * A);
                h = fmaf(dA, h, dt * xc * Bv);
                float ctr = h * Cv;
                ctr = dpp_add(ctr, 0xB1);
                ctr = dpp_add(ctr, 0x4E);
                ctr = dpp_add(ctr, 0x141);
                ctr = dpp_add(ctr, 0x140);
                if (n == 2 * jp + 1) yreg = ctr;
            }
        }
        const int lr = l0 + n;
        const unsigned short xcu16 =
            ((const unsigned short*)sdx2)[(lr >> 1) * 64 + g * 4 + 1 + 2 * (lr & 1)];
        const float xcf = __uint_as_float(((unsigned)xcu16) << 16);
        const float ze = __uint_as_float(((unsigned)sz[lr][g]) << 16);
        yb[(row0 + lr) * DINNER + d] =
            __float2bfloat16((yreg + xcf * Dp) * siluf(ze));
    }
}

// out[m,n] = b2[n] + sum_k h[m,k]*W2[n,k]  (h in bf16)
__global__ __launch_bounds__(256)
void ffn2_kernel(const __hip_bfloat16* __restrict__ h, const float* __restrict__ W2,
                 const float* __restrict__ b2, float* __restrict__ out)
{
    const int idx = blockIdx.x * 256 + threadIdx.x;   // MROWS*32
    const int n = idx & 31;
    const int m = idx >> 5;
    if (n >= 18) return;
    const unsigned short* hr = (const unsigned short*)(h + (size_t)m * DMODEL);
    const float* wr = W2 + (size_t)n * DMODEL;
    float acc = b2[n];
    for (int k = 0; k < DMODEL; k += 8) {
        const uint4 hv = *(const uint4*)(hr + k);
        const float4 w0 = *(const float4*)(wr + k);
        const float4 w1 = *(const float4*)(wr + k + 4);
        acc = fmaf(bflo(hv.x), w0.x, acc);
        acc = fmaf(bfhi(hv.x), w0.y, acc);
        acc = fmaf(bflo(hv.y), w0.z, acc);
        acc = fmaf(bfhi(hv.y), w0.w, acc);
        acc = fmaf(bflo(hv.z), w1.x, acc);
        acc = fmaf(bfhi(hv.z), w1.y, acc);
        acc = fmaf(bflo(hv.w), w1.z, acc);
        acc = fmaf(bfhi(hv.w), w1.w, acc);
    }
    out[(size_t)m * 18 + n] = acc;
}

extern "C" void kernel_launch(void* const* d_in, const int* in_sizes, int n_in,
                              void* d_out, int out_size, void* d_ws, size_t ws_size,
                              hipStream_t stream)
{
    const float* obss    = (const float*)d_in[0];
    const int*   actions = (const int*)  d_in[1];
    const float* obs_W   = (const float*)d_in[2];
    const float* obs_b   = (const float*)d_in[3];
    const float* act_emb = (const float*)d_in[4];
    const float* pos_emb = (const float*)d_in[5];
    const float* W_in    = (const float*)d_in[6];
    const float* conv_w  = (const float*)d_in[7];
    const float* conv_b  = (const float*)d_in[8];
    const float* W_x     = (const float*)d_in[9];
    const float* W_dt    = (const float*)d_in[10];
    const float* b_dt    = (const float*)d_in[11];
    const float* A_log   = (const float*)d_in[12];
    const float* D_p     = (const float*)d_in[13];
    const float* W_out   = (const float*)d_in[14];
    const float* ffn_W1  = (const float*)d_in[15];
    const float* ffn_b1  = (const float*)d_in[16];
    const float* ffn_W2  = (const float*)d_in[17];
    const float* ffn_b2  = (const float*)d_in[18];
    float* out = (float*)d_out;

    const size_t MiB = 1024 * 1024;
    char* base = (char*)d_ws;
    __hip_bfloat16* xb    = (__hip_bfloat16*)(base);
    __hip_bfloat16* xzb   = (__hip_bfloat16*)(base + 8 * MiB);
    __hip_bfloat16* xcb   = (__hip_bfloat16*)(base + 40 * MiB);
    __hip_bfloat16* dtb   = (__hip_bfloat16*)(base + 56 * MiB);
    __hip_bfloat16* yb    = (__hip_bfloat16*)(base + 88 * MiB);
    float*          xdt   = (float*)(base + 104 * MiB);
    __hip_bfloat16* bcb   = (__hip_bfloat16*)(base + 105 * MiB);
    __hip_bfloat16* wbuf  = (__hip_bfloat16*)(base + 106 * MiB);
    __hip_bfloat16* wxb   = (__hip_bfloat16*)(base + 110 * MiB);
    __hip_bfloat16* obssb = (__hip_bfloat16*)(base + 8 * MiB);
    __hip_bfloat16* hbuf  = (__hip_bfloat16*)(base + 8 * MiB);

    // --- prologue ---
    cast_bf16_kernel<<<(MROWS * OBSDIM / 4) / 256, 256, 0, stream>>>(obss, obssb, MROWS * OBSDIM / 4);
    cast_pad_kernel<<<(512 * OBSDIM / 4) / 256, 256, 0, stream>>>(obs_W, wbuf, OBSOUT, OBSDIM / 4, 512 * OBSDIM / 4);
    embed_kernel<<<MROWS * ADIM / 256, 256, 0, stream>>>(actions, act_emb, pos_emb, xb);
    gemm_mfma<MEPI_TOK><<<4 * (MROWS / 128), 256, 0, stream>>>(
        obssb, OBSDIM, wbuf, nullptr, 0, xb, DMODEL, ADIM, OBSOUT, OBSDIM, 4, obs_b, pos_emb);

    for (int i = 0; i < NLAYERS; ++i) {
        // W_in: xzb = bf16(xb @ W_in^T), ld 2048 (xi | z)
        cast_bf16_kernel<<<(2 * DINNER * DMODEL / 4) / 256, 256, 0, stream>>>(
            W_in + (size_t)i * 2 * DINNER * DMODEL, wbuf, 2 * DINNER * DMODEL / 4);
        gemm_mfma<MEPI_BF16><<<(2 * DINNER / 128) * (MROWS / 128), 256, 0, stream>>>(
            xb, DMODEL, wbuf, nullptr, 0, xzb, 2 * DINNER, 0, 2 * DINNER, DMODEL,
            2 * DINNER / 128, nullptr, nullptr);
        conv_silu_kernel<<<MROWS * DINNER / 256, 256, 0, stream>>>(
            xzb, conv_w + (size_t)i * DINNER * 4, conv_b + (size_t)i * DINNER, xcb);
        // W_x (mfma, split): xdt = xcb @ W_x^T[:32] (f32), bcb = pair-interleaved bf16 (B,C)
        cast_pad_kernel<<<(128 * DINNER / 4) / 256, 256, 0, stream>>>(
            W_x + (size_t)i * 64 * DINNER, wxb, 64, DINNER / 4, 128 * DINNER / 4);
        gemm_mfma<MEPI_SPLIT><<<MROWS / 128, 256, 0, stream>>>(
            xcb, DINNER, wxb, xdt, 0, bcb, 0, 0, 64, DINNER, 1, nullptr, nullptr);
        // W_dt (f32, K=32, softplus): dtb (bf16)
        gemm_f32_sp<<<dim3(DINNER / 64, MROWS / 64), 256, 0, stream>>>(
            xdt, 32, W_dt + (size_t)i * DINNER * DTRANK, dtb, DINNER, DINNER, DTRANK,
            b_dt + (size_t)i * DINNER);
        scan_kernel<<<(32 * DINNER) / 16, 256, 0, stream>>>(
            dtb, bcb, xcb, xzb + DINNER, A_log + (size_t)i * DINNER * DSTATE,
            D_p + (size_t)i * DINNER, yb);
        // W_out: xb = bf16(yb @ W_out^T)
        cast_bf16_kernel<<<(DMODEL * DINNER / 4) / 256, 256, 0, stream>>>(
            W_out + (size_t)i * DMODEL * DINNER, wbuf, DMODEL * DINNER / 4);
        gemm_mfma<MEPI_BF16><<<(DMODEL / 128) * (MROWS / 128), 256, 0, stream>>>(
            yb, DINNER, wbuf, nullptr, 0, xb, DMODEL, 0, DMODEL, DINNER,
            DMODEL / 128, nullptr, nullptr);
    }

    cast_bf16_kernel<<<(DMODEL * DMODEL / 4) / 256, 256, 0, stream>>>(ffn_W1, wbuf, DMODEL * DMODEL / 4);
    gemm_mfma<MEPI_RELUB><<<(DMODEL / 128) * (MROWS / 128), 256, 0, stream>>>(
        xb, DMODEL, wbuf, nullptr, 0, hbuf, DMODEL, 0, DMODEL, DMODEL,
        DMODEL / 128, ffn_b1, nullptr);
    ffn2_kernel<<<MROWS * 32 / 256, 256, 0, stream>>>(hbuf, ffn_W2, ffn_b2, out);
}